// Round 2
// baseline (5767.122 us; speedup 1.0000x reference)
//
#include <hip/hip_runtime.h>
#include <hip/hip_bf16.h>

typedef __hip_bfloat16 bf16;

#define BB 8
#define HH 16
#define NTOK 2048
#define DD 64
#define HID 256
#define NIT 4
#define CH 512           // chunk rows per inner step
#define NP 128           // B*H pairs
#define INV_CD 3.0517578125e-05f  // 1/(CH*DD) = 1/32768

// jax.nn.gelu default approximate=True: 0.5x(1+tanh(sqrt(2/pi)(x+0.044715x^3)))
__device__ __forceinline__ float gelu_f(float x){
    const float c0 = 0.7978845608028654f, c1 = 0.044715f;
    float u = c0*(x + c1*x*x*x);
    float t = tanhf(u);
    return 0.5f*x*(1.0f+t);
}
__device__ __forceinline__ float gelu_grad(float x){
    const float c0 = 0.7978845608028654f, c1 = 0.044715f;
    float x2 = x*x;
    float u = c0*(x + c1*x2*x);
    float t = tanhf(u);
    return 0.5f*(1.0f+t) + 0.5f*x*(1.0f-t*t)*c0*(1.0f+3.0f*c1*x2);
}

// Broadcast input weights (per-h) into per-pair f32 master copies.
__global__ __launch_bounds__(256) void k_init(const float* __restrict__ W1in,
                                              const float* __restrict__ W2in,
                                              float* __restrict__ W1s,
                                              float* __restrict__ W2s){
    int idx = blockIdx.x*256 + threadIdx.x;      // 0 .. NP*16384-1
    int p = idx >> 14;                           // pair
    int r = idx & 16383;
    int h = p & 15;
    W1s[idx] = W1in[h*16384 + r];
    W2s[idx] = W2in[h*16384 + r];
}

// z = x @ W1 for chunk t. One block = (pair, 64-row tile). z stored bf16 in d_out scratch.
__global__ __launch_bounds__(256) void k_z(const float* __restrict__ kin,
                                           const float* __restrict__ W1s,
                                           bf16* __restrict__ zbuf, int t){
    int p = blockIdx.x >> 3, rt = blockIdx.x & 7;
    int tid = threadIdx.x;
    int m0 = rt*64;
    __shared__ float xt[64*64];
    const float* xb = kin + ((size_t)p*NTOK + (size_t)t*CH + m0)*DD;
    for (int i=0;i<16;i++){ int f=i*256+tid; xt[f] = xb[f]; }
    __syncthreads();
    const float* w1 = W1s + (size_t)p*DD*HID;
    float acc[64];
    #pragma unroll
    for (int m=0;m<64;m++) acc[m]=0.f;
    for (int d=0;d<DD;d++){
        float w = w1[d*HID+tid];
        #pragma unroll
        for (int m=0;m<64;m++) acc[m] = fmaf(xt[m*64+d], w, acc[m]);
    }
    bf16* z = zbuf + ((size_t)p*CH+m0)*HID;
    for (int m=0;m<64;m++) z[m*HID+tid] = __float2bfloat16(acc[m]);
}

// out = gelu(z) @ W2 ; e = (out - y)/32768. One block = (pair, 32-row tile).
__global__ __launch_bounds__(256) void k_he(const bf16* __restrict__ zbuf,
                                            const float* __restrict__ W2s,
                                            const float* __restrict__ vin,
                                            float* __restrict__ ebuf, int t){
    int p = blockIdx.x >> 4, rt = blockIdx.x & 15;
    int m0 = rt*32, tid = threadIdx.x;
    __shared__ float hl[32*256];   // 32 KB
    const bf16* z = zbuf + ((size_t)p*CH+m0)*HID;
    for (int i=0;i<32;i++) hl[i*256+tid] = gelu_f(__bfloat162float(z[i*256+tid]));
    __syncthreads();
    int o = tid & 63, ms = tid >> 6;
    const float* w2 = W2s + (size_t)p*HID*DD;
    float acc[8];
    #pragma unroll
    for (int j=0;j<8;j++) acc[j]=0.f;
    for (int e=0;e<HID;e++){
        float w = w2[e*64+o];
        #pragma unroll
        for (int j=0;j<8;j++) acc[j] = fmaf(hl[(ms*8+j)*256+e], w, acc[j]);
    }
    const float* y = vin + ((size_t)p*NTOK + (size_t)t*CH + m0)*DD;
    float* eo = ebuf + ((size_t)p*CH+m0)*DD;
    #pragma unroll
    for (int j=0;j<8;j++){
        int m = ms*8+j;
        eo[m*64+o] = (acc[j] - y[m*64+o]) * INV_CD;
    }
}

// dW1 = x^T (e @ W2_old^T * gelu'(z)); W1 -= dW1 (in place; nothing below reads W1_old).
// One block per pair, 512 threads: thread = (e' = tid&255, dg = tid>>8 owning 32 d's).
__global__ __launch_bounds__(512) void k_dW1(const float* __restrict__ kin,
                                             const bf16* __restrict__ zbuf,
                                             const float* __restrict__ ebuf,
                                             const float* __restrict__ W2s,
                                             float* __restrict__ W1s, int t){
    int p = blockIdx.x, tid = threadIdx.x;
    int ep = tid & 255, dg = tid >> 8;
    const float* w2 = W2s + (size_t)p*HID*DD;
    float w2r[64];                      // this thread's row of W2 (e'-th row)
    #pragma unroll
    for (int o=0;o<64;o++) w2r[o] = w2[ep*64+o];
    float acc[32];
    #pragma unroll
    for (int i=0;i<32;i++) acc[i]=0.f;
    const float* x  = kin  + ((size_t)p*NTOK + (size_t)t*CH)*DD;
    const bf16* z  = zbuf + (size_t)p*CH*HID;
    const float* er = ebuf + (size_t)p*CH*DD;
    for (int m=0;m<CH;m++){
        float zv = __bfloat162float(z[m*256+ep]);
        float gp = gelu_grad(zv);
        float dh = 0.f;
        #pragma unroll
        for (int o=0;o<64;o++) dh = fmaf(er[m*64+o], w2r[o], dh);
        float dz = dh*gp;
        const float* xr = x + m*64 + dg*32;
        #pragma unroll
        for (int i=0;i<32;i++) acc[i] = fmaf(xr[i], dz, acc[i]);
    }
    float* w1 = W1s + (size_t)p*DD*HID;
    #pragma unroll
    for (int i=0;i<32;i++) w1[(dg*32+i)*HID+ep] -= acc[i];
}

// dW2 = gelu(z)^T e ; W2 -= dW2 (in place, runs AFTER k_dW1 consumed W2_old).
// One block per pair, 512 threads: thread = (o = tid&63, eg = tid>>6 owning 32 e's).
__global__ __launch_bounds__(512) void k_dW2(const bf16* __restrict__ zbuf,
                                             const float* __restrict__ ebuf,
                                             float* __restrict__ W2s){
    int p = blockIdx.x, tid = threadIdx.x;
    int o = tid & 63, eg = tid >> 6;
    __shared__ float hl[8*256];
    __shared__ float el[8*64];
    const bf16* z  = zbuf + (size_t)p*CH*HID;
    const float* er = ebuf + (size_t)p*CH*DD;
    float acc[32];
    #pragma unroll
    for (int i=0;i<32;i++) acc[i]=0.f;
    for (int mb=0; mb<CH/8; mb++){
        __syncthreads();
        #pragma unroll
        for (int i=0;i<4;i++){ int f=i*512+tid; hl[f] = gelu_f(__bfloat162float(z[(size_t)mb*2048 + f])); }
        el[tid] = er[(size_t)mb*512 + tid];
        __syncthreads();
        #pragma unroll
        for (int r=0;r<8;r++){
            float ev = el[r*64+o];
            #pragma unroll
            for (int i=0;i<32;i++) acc[i] = fmaf(hl[r*256 + eg*32 + i], ev, acc[i]);
        }
    }
    float* w2 = W2s + (size_t)p*HID*DD;
    #pragma unroll
    for (int i=0;i<32;i++) w2[(eg*32+i)*64+o] -= acc[i];
}

// out = gelu(q @ W1_final) @ W2_final, written as (B, N, H*D) f32. Overwrites z scratch
// (k_apply does not read z, so aliasing with d_out is safe).
__global__ __launch_bounds__(256) void k_apply(const float* __restrict__ qin,
                                               const float* __restrict__ W1s,
                                               const float* __restrict__ W2s,
                                               float* __restrict__ out){
    int p = blockIdx.x >> 6, rt = blockIdx.x & 63;
    int m0 = rt*32, tid = threadIdx.x;
    int b = p >> 4, h = p & 15;
    __shared__ float xt[32*64];    // 8 KB
    __shared__ float hl[32*256];   // 32 KB
    const float* x = qin + ((size_t)p*NTOK + m0)*DD;
    for (int i=0;i<8;i++){ int f=i*256+tid; xt[f]=x[f]; }
    __syncthreads();
    const float* w1 = W1s + (size_t)p*DD*HID;
    float a1[32];
    #pragma unroll
    for (int m=0;m<32;m++) a1[m]=0.f;
    for (int d=0;d<DD;d++){
        float w = w1[d*HID+tid];
        #pragma unroll
        for (int m=0;m<32;m++) a1[m] = fmaf(xt[m*64+d], w, a1[m]);
    }
    for (int m=0;m<32;m++) hl[m*256+tid] = gelu_f(a1[m]);
    __syncthreads();
    int o = tid & 63, ms = tid >> 6;
    const float* w2 = W2s + (size_t)p*HID*DD;
    float a2[8];
    #pragma unroll
    for (int j=0;j<8;j++) a2[j]=0.f;
    for (int e=0;e<HID;e++){
        float w = w2[e*64+o];
        #pragma unroll
        for (int j=0;j<8;j++) a2[j] = fmaf(hl[(ms*8+j)*256+e], w, a2[j]);
    }
    #pragma unroll
    for (int j=0;j<8;j++){
        int n = m0 + ms*8 + j;
        out[((size_t)b*NTOK+n)*(HH*DD) + h*64 + o] = a2[j];
    }
}

extern "C" void kernel_launch(void* const* d_in, const int* in_sizes, int n_in,
                              void* d_out, int out_size, void* d_ws, size_t ws_size,
                              hipStream_t stream) {
    (void)in_sizes; (void)n_in; (void)out_size; (void)ws_size;
    const float* q  = (const float*)d_in[0];
    const float* k  = (const float*)d_in[1];
    const float* v  = (const float*)d_in[2];
    const float* W1 = (const float*)d_in[3];
    const float* W2 = (const float*)d_in[4];
    float* out = (float*)d_out;

    // ws: master weights (f32) + e-matrix (f32). 32 MB total.
    float* W1s  = (float*)d_ws;                 // NP*64*256
    float* W2s  = W1s + (size_t)NP*DD*HID;      // NP*256*64
    float* Ebuf = W2s + (size_t)NP*HID*DD;      // NP*512*64
    // z scratch (bf16) lives in the first 32 MB of d_out (out_size elements >= 16.7M),
    // fully overwritten by k_apply at the end (k_apply never reads z).
    bf16* Zbuf = (bf16*)d_out;

    k_init<<<8192, 256, 0, stream>>>(W1, W2, W1s, W2s);
    for (int t=0; t<NIT; t++){
        k_z  <<<1024, 256, 0, stream>>>(k, W1s, Zbuf, t);
        k_he <<<2048, 256, 0, stream>>>(Zbuf, W2s, v, Ebuf, t);
        k_dW1<<<NP,   512, 0, stream>>>(k, Zbuf, Ebuf, W2s, W1s, t);  // reads W2_old
        k_dW2<<<NP,   512, 0, stream>>>(Zbuf, Ebuf, W2s);             // then W2 update
    }
    k_apply<<<8192, 256, 0, stream>>>(q, W1s, W2s, out);
}

// Round 3
// 2204.261 us; speedup vs baseline: 2.6164x; 2.6164x over previous
//
#include <hip/hip_runtime.h>
#include <hip/hip_bf16.h>

typedef __hip_bfloat16 bf16;

#define BB 8
#define HH 16
#define NTOK 2048
#define DD 64
#define HID 256
#define NIT 4
#define CH 512           // chunk rows per inner step
#define NP 128           // B*H pairs
#define INV_CD 3.0517578125e-05f  // 1/(CH*DD) = 1/32768

// jax.nn.gelu default approximate=True: 0.5x(1+tanh(sqrt(2/pi)(x+0.044715x^3)))
__device__ __forceinline__ float gelu_f(float x){
    const float c0 = 0.7978845608028654f, c1 = 0.044715f;
    float u = c0*(x + c1*x*x*x);
    float t = tanhf(u);
    return 0.5f*x*(1.0f+t);
}
__device__ __forceinline__ float gelu_grad(float x){
    const float c0 = 0.7978845608028654f, c1 = 0.044715f;
    float x2 = x*x;
    float u = c0*(x + c1*x2*x);
    float t = tanhf(u);
    return 0.5f*(1.0f+t) + 0.5f*x*(1.0f-t*t)*c0*(1.0f+3.0f*c1*x2);
}

// Broadcast input weights (per-h) into per-pair f32 master copies.
__global__ __launch_bounds__(256) void k_init(const float* __restrict__ W1in,
                                              const float* __restrict__ W2in,
                                              float* __restrict__ W1s,
                                              float* __restrict__ W2s){
    int idx = blockIdx.x*256 + threadIdx.x;      // 0 .. NP*16384-1
    int p = idx >> 14;                           // pair
    int r = idx & 16383;
    int h = p & 15;
    W1s[idx] = W1in[h*16384 + r];
    W2s[idx] = W2in[h*16384 + r];
}

// z = x @ W1 for chunk t. One block = (pair, 64-row tile). z stored bf16 in d_out scratch.
__global__ __launch_bounds__(256) void k_z(const float* __restrict__ kin,
                                           const float* __restrict__ W1s,
                                           bf16* __restrict__ zbuf, int t){
    int p = blockIdx.x >> 3, rt = blockIdx.x & 7;
    int tid = threadIdx.x;
    int m0 = rt*64;
    __shared__ float xt[64*64];
    const float* xb = kin + ((size_t)p*NTOK + (size_t)t*CH + m0)*DD;
    for (int i=0;i<16;i++){ int f=i*256+tid; xt[f] = xb[f]; }
    __syncthreads();
    const float* w1 = W1s + (size_t)p*DD*HID;
    float acc[64];
    #pragma unroll
    for (int m=0;m<64;m++) acc[m]=0.f;
    for (int d=0;d<DD;d++){
        float w = w1[d*HID+tid];
        #pragma unroll
        for (int m=0;m<64;m++) acc[m] = fmaf(xt[m*64+d], w, acc[m]);
    }
    bf16* z = zbuf + ((size_t)p*CH+m0)*HID;
    for (int m=0;m<64;m++) z[m*HID+tid] = __float2bfloat16(acc[m]);
}

// out = gelu(z) @ W2 ; e = (out - y)/32768. One block = (pair, 32-row tile).
__global__ __launch_bounds__(256) void k_he(const bf16* __restrict__ zbuf,
                                            const float* __restrict__ W2s,
                                            const float* __restrict__ vin,
                                            float* __restrict__ ebuf, int t){
    int p = blockIdx.x >> 4, rt = blockIdx.x & 15;
    int m0 = rt*32, tid = threadIdx.x;
    __shared__ float hl[32*256];   // 32 KB
    const bf16* z = zbuf + ((size_t)p*CH+m0)*HID;
    for (int i=0;i<32;i++) hl[i*256+tid] = gelu_f(__bfloat162float(z[i*256+tid]));
    __syncthreads();
    int o = tid & 63, ms = tid >> 6;
    const float* w2 = W2s + (size_t)p*HID*DD;
    float acc[8];
    #pragma unroll
    for (int j=0;j<8;j++) acc[j]=0.f;
    for (int e=0;e<HID;e++){
        float w = w2[e*64+o];
        #pragma unroll
        for (int j=0;j<8;j++) acc[j] = fmaf(hl[(ms*8+j)*256+e], w, acc[j]);
    }
    const float* y = vin + ((size_t)p*NTOK + (size_t)t*CH + m0)*DD;
    float* eo = ebuf + ((size_t)p*CH+m0)*DD;
    #pragma unroll
    for (int j=0;j<8;j++){
        int m = ms*8+j;
        eo[m*64+o] = (acc[j] - y[m*64+o]) * INV_CD;
    }
}

// dz = (e @ W2_old^T) * gelu'(z), stored bf16. One block = (pair, 64-row split).
// Thread owns column e' = tid; W2 row e' in 64 regs; e-tile staged in LDS.
__global__ __launch_bounds__(256) void k_dz(const bf16* __restrict__ zbuf,
                                            const float* __restrict__ ebuf,
                                            const float* __restrict__ W2s,
                                            bf16* __restrict__ dzbuf){
    int p = blockIdx.x >> 3, s = blockIdx.x & 7;
    int tid = threadIdx.x;
    __shared__ float el[64*64];    // 16 KB
    const float* er = ebuf + ((size_t)p*CH + s*64)*DD;
    for (int i=0;i<16;i++){ int f=i*256+tid; el[f] = er[f]; }
    const float* w2 = W2s + (size_t)p*HID*DD + (size_t)tid*DD;
    float w2r[64];
    #pragma unroll
    for (int o=0;o<64;o++) w2r[o] = w2[o];
    __syncthreads();
    const bf16* z  = zbuf  + ((size_t)p*CH + s*64)*HID;
    bf16* dz       = dzbuf + ((size_t)p*CH + s*64)*HID;
    for (int m=0;m<64;m++){
        float dh = 0.f;
        #pragma unroll
        for (int o=0;o<64;o++) dh = fmaf(el[m*64+o], w2r[o], dh);
        float zv = __bfloat162float(z[m*HID+tid]);
        dz[m*HID+tid] = __float2bfloat16(dh * gelu_grad(zv));
    }
}

// dW1 = x^T dz over a 64-row split; atomicAdd(-dW1) into master W1.
// Thread owns column e' = tid, 64 d-accumulators; x-tile staged in LDS (broadcast reads).
__global__ __launch_bounds__(256) void k_dW1(const float* __restrict__ kin,
                                             const bf16* __restrict__ dzbuf,
                                             float* __restrict__ W1s, int t){
    int p = blockIdx.x >> 3, s = blockIdx.x & 7;
    int tid = threadIdx.x;
    __shared__ float xt[64*64];    // 16 KB
    const float* x = kin + ((size_t)p*NTOK + (size_t)t*CH + s*64)*DD;
    for (int i=0;i<16;i++){ int f=i*256+tid; xt[f] = x[f]; }
    __syncthreads();
    const bf16* dz = dzbuf + ((size_t)p*CH + s*64)*HID;
    float acc[64];
    #pragma unroll
    for (int d=0;d<64;d++) acc[d]=0.f;
    for (int m=0;m<64;m++){
        float dzv = __bfloat162float(dz[m*HID+tid]);
        #pragma unroll
        for (int d=0;d<64;d++) acc[d] = fmaf(xt[m*64+d], dzv, acc[d]);
    }
    float* w1 = W1s + (size_t)p*DD*HID;
    for (int d=0;d<64;d++) atomicAdd(&w1[d*HID+tid], -acc[d]);
}

// dW2 = gelu(z)^T e over a 64-row split; atomicAdd(-dW2) into master W2.
// Runs AFTER k_dz consumed W2_old. Thread = (o = tid&63, eg = tid>>6 owning 64 e's).
__global__ __launch_bounds__(256) void k_dW2(const bf16* __restrict__ zbuf,
                                             const float* __restrict__ ebuf,
                                             float* __restrict__ W2s){
    int p = blockIdx.x >> 3, s = blockIdx.x & 7;
    int tid = threadIdx.x;
    int o = tid & 63, eg = tid >> 6;
    __shared__ float hl[8*256];    // 8 KB
    __shared__ float el[8*64];     // 2 KB
    const bf16* z  = zbuf + ((size_t)p*CH + s*64)*HID;
    const float* er = ebuf + ((size_t)p*CH + s*64)*DD;
    float acc[64];
    #pragma unroll
    for (int i=0;i<64;i++) acc[i]=0.f;
    for (int mb=0; mb<8; mb++){
        __syncthreads();
        #pragma unroll
        for (int i=0;i<8;i++){ int f=i*256+tid; hl[f] = gelu_f(__bfloat162float(z[mb*8*HID + f])); }
        #pragma unroll
        for (int i=0;i<2;i++){ int f=i*256+tid; el[f] = er[mb*8*DD + f]; }
        __syncthreads();
        #pragma unroll
        for (int r=0;r<8;r++){
            float ev = el[r*64+o];
            #pragma unroll
            for (int i=0;i<64;i++) acc[i] = fmaf(hl[r*256 + eg*64 + i], ev, acc[i]);
        }
    }
    float* w2 = W2s + (size_t)p*HID*DD;
    for (int i=0;i<64;i++) atomicAdd(&w2[(eg*64+i)*DD + o], -acc[i]);
}

// out = gelu(q @ W1_final) @ W2_final, written as (B, N, H*D) f32. Overwrites z/dz scratch
// (k_apply does not read them, so aliasing with d_out is safe).
__global__ __launch_bounds__(256) void k_apply(const float* __restrict__ qin,
                                               const float* __restrict__ W1s,
                                               const float* __restrict__ W2s,
                                               float* __restrict__ out){
    int p = blockIdx.x >> 6, rt = blockIdx.x & 63;
    int m0 = rt*32, tid = threadIdx.x;
    int b = p >> 4, h = p & 15;
    __shared__ float xt[32*64];    // 8 KB
    __shared__ float hl[32*256];   // 32 KB
    const float* x = qin + ((size_t)p*NTOK + m0)*DD;
    for (int i=0;i<8;i++){ int f=i*256+tid; xt[f]=x[f]; }
    __syncthreads();
    const float* w1 = W1s + (size_t)p*DD*HID;
    float a1[32];
    #pragma unroll
    for (int m=0;m<32;m++) a1[m]=0.f;
    for (int d=0;d<DD;d++){
        float w = w1[d*HID+tid];
        #pragma unroll
        for (int m=0;m<32;m++) a1[m] = fmaf(xt[m*64+d], w, a1[m]);
    }
    for (int m=0;m<32;m++) hl[m*256+tid] = gelu_f(a1[m]);
    __syncthreads();
    int o = tid & 63, ms = tid >> 6;
    const float* w2 = W2s + (size_t)p*HID*DD;
    float a2[8];
    #pragma unroll
    for (int j=0;j<8;j++) a2[j]=0.f;
    for (int e=0;e<HID;e++){
        float w = w2[e*64+o];
        #pragma unroll
        for (int j=0;j<8;j++) a2[j] = fmaf(hl[(ms*8+j)*256+e], w, a2[j]);
    }
    #pragma unroll
    for (int j=0;j<8;j++){
        int n = m0 + ms*8 + j;
        out[((size_t)b*NTOK+n)*(HH*DD) + h*64 + o] = a2[j];
    }
}

extern "C" void kernel_launch(void* const* d_in, const int* in_sizes, int n_in,
                              void* d_out, int out_size, void* d_ws, size_t ws_size,
                              hipStream_t stream) {
    (void)in_sizes; (void)n_in; (void)out_size; (void)ws_size;
    const float* q  = (const float*)d_in[0];
    const float* k  = (const float*)d_in[1];
    const float* v  = (const float*)d_in[2];
    const float* W1 = (const float*)d_in[3];
    const float* W2 = (const float*)d_in[4];
    float* out = (float*)d_out;

    // ws: master weights (f32) + e-matrix (f32). 32 MB total.
    float* W1s  = (float*)d_ws;                 // NP*64*256
    float* W2s  = W1s + (size_t)NP*DD*HID;      // NP*256*64
    float* Ebuf = W2s + (size_t)NP*HID*DD;      // NP*512*64
    // z scratch (bf16, first half) and dz scratch (bf16, second half) live in d_out:
    // out_size f32 elements = 2*NP*CH*HID bf16 slots — exact fit. k_apply overwrites all.
    bf16* Zbuf  = (bf16*)d_out;
    bf16* DZbuf = Zbuf + (size_t)NP*CH*HID;

    k_init<<<8192, 256, 0, stream>>>(W1, W2, W1s, W2s);
    for (int t=0; t<NIT; t++){
        k_z  <<<1024, 256, 0, stream>>>(k, W1s, Zbuf, t);
        k_he <<<2048, 256, 0, stream>>>(Zbuf, W2s, v, Ebuf, t);
        k_dz <<<1024, 256, 0, stream>>>(Zbuf, Ebuf, W2s, DZbuf);      // reads W2_old
        k_dW2<<<1024, 256, 0, stream>>>(Zbuf, Ebuf, W2s);             // then W2 update
        k_dW1<<<1024, 256, 0, stream>>>(k, DZbuf, W1s, t);            // W1 update
    }
    k_apply<<<8192, 256, 0, stream>>>(q, W1s, W2s, out);
}

// Round 4
// 1220.161 us; speedup vs baseline: 4.7265x; 1.8065x over previous
//
#include <hip/hip_runtime.h>
#include <hip/hip_bf16.h>

typedef __hip_bfloat16 bf16;
typedef __attribute__((ext_vector_type(8))) short frag8;   // 8 bf16 = 4 VGPR
typedef __attribute__((ext_vector_type(4))) float frag4f;  // MFMA C/D
typedef __attribute__((ext_vector_type(4))) short short4v; // 8B packed store

#define BB 8
#define HH 16
#define NTOK 2048
#define DD 64
#define HID 256
#define NIT 4
#define CH 512
#define NP 128
#define INV_CD 3.0517578125e-05f  // 1/(CH*DD)

#define MFMA(a,b,c) __builtin_amdgcn_mfma_f32_16x16x32_bf16((a),(b),(c),0,0,0)

__device__ __forceinline__ short f2b(float f){
    union { __hip_bfloat16 b; short s; } u;
    u.b = __float2bfloat16(f);
    return u.s;
}

__device__ __forceinline__ float gelu_f(float x){
    const float c0 = 0.7978845608028654f, c1 = 0.044715f;
    float u = c0*(x + c1*x*x*x);
    float t = tanhf(u);
    return 0.5f*x*(1.0f+t);
}
__device__ __forceinline__ float gelu_grad(float x){
    const float c0 = 0.7978845608028654f, c1 = 0.044715f;
    float x2 = x*x;
    float u = c0*(x + c1*x2*x);
    float t = tanhf(u);
    return 0.5f*(1.0f+t) + 0.5f*x*(1.0f-t*t)*c0*(1.0f+3.0f*c1*x2);
}

// Broadcast input weights (per-h) into per-pair f32 master copies.
__global__ __launch_bounds__(256) void k_init(const float* __restrict__ W1in,
                                              const float* __restrict__ W2in,
                                              float* __restrict__ W1s,
                                              float* __restrict__ W2s){
    int idx = blockIdx.x*256 + threadIdx.x;
    int p = idx >> 14, r = idx & 16383, h = p & 15;
    W1s[idx] = W1in[h*16384 + r];
    W2s[idx] = W2in[h*16384 + r];
}

// Snapshot f32 masters -> pre-swizzled bf16 B-fragment layouts.
// Frag layout: B[k][n], n = nt*16 + (lane&15), k = kk*32 + (lane>>4)*8 + j.
// Storage: buf[((p*32 + slot)*64 + lane)*8 + j], one coalesced 16B load per lane.
__global__ __launch_bounds__(256) void k_castW(const float* __restrict__ W1s,
                                               const float* __restrict__ W2s,
                                               short* __restrict__ W1p,
                                               short* __restrict__ W2p,
                                               short* __restrict__ W2tp){
    int g = blockIdx.x*256 + threadIdx.x;        // NP*96*64 threads
    int lane = g & 63;
    int slot = (g >> 6) % 96;
    int p = g / (96*64);
    int q = lane >> 4, ln = lane & 15;
    if (slot < 32){                              // W1p: B = W1 (64x256), nt16 x kk2
        int nt = slot >> 1, kk = slot & 1;
        const float* src = W1s + (size_t)p*16384;
        short* dst = W1p + (((size_t)p*32 + slot)*64 + lane)*8;
        #pragma unroll
        for (int j=0;j<8;j++){
            int k = kk*32 + q*8 + j, n = nt*16 + ln;
            dst[j] = f2b(src[k*HID + n]);
        }
    } else if (slot < 64){                       // W2p: B = W2 (256x64), nt4 x kk8
        int s2 = slot - 32;
        int nt = s2 >> 3, kk = s2 & 7;
        const float* src = W2s + (size_t)p*16384;
        short* dst = W2p + (((size_t)p*32 + s2)*64 + lane)*8;
        #pragma unroll
        for (int j=0;j<8;j++){
            int e = kk*32 + q*8 + j, o = nt*16 + ln;
            dst[j] = f2b(src[e*DD + o]);
        }
    } else {                                     // W2tp: B = W2^T (64x256), nt16 x kk2
        int s2 = slot - 64;
        int nt = s2 >> 1, kk = s2 & 1;
        const float* src = W2s + (size_t)p*16384;
        short* dst = W2tp + (((size_t)p*32 + s2)*64 + lane)*8;
        #pragma unroll
        for (int j=0;j<8;j++){
            int o = kk*32 + q*8 + j, e = nt*16 + ln;
            dst[j] = f2b(src[e*DD + o]);
        }
    }
}

// Fused forward + dz for one step:
//   z = x@W1 (kept in f32 accum regs), h = gelu(z) -> LDS + hT,
//   out = h@W2, e = (out-y)*s -> LDS + eT,
//   dz = (e@W2^T) * gelu'(z_regs) -> dzT.
// Block = (pair, 64-row m-tile); wave w owns rows 16w..16w+15.
__global__ __launch_bounds__(256) void k_fwd(const float* __restrict__ kin,
                                             const float* __restrict__ vin,
                                             const short* __restrict__ W1p,
                                             const short* __restrict__ W2p,
                                             const short* __restrict__ W2tp,
                                             short* __restrict__ eT,
                                             short* __restrict__ hT,
                                             short* __restrict__ dzT, int t){
    int p = blockIdx.x >> 3, mt = blockIdx.x & 7;
    int tid = threadIdx.x;
    int w = tid >> 6, lane = tid & 63, q = lane >> 4, ln = lane & 15;
    int m0 = mt*64;
    __shared__ short hl[64*264];   // h row-major, pad 264 (33 KB)
    __shared__ short el[64*72];    // e row-major, pad 72 (9 KB)

    // ---- z = x @ W1 ----  A-frags built from f32 global x
    const float* xbase = kin + ((size_t)p*NTOK + (size_t)t*CH + m0 + w*16 + ln)*DD;
    frag8 af[2];
    #pragma unroll
    for (int kk=0;kk<2;kk++){
        const float* xr = xbase + kk*32 + q*8;
        float4 u0 = *(const float4*)xr;
        float4 u1 = *(const float4*)(xr+4);
        frag8 a;
        a[0]=f2b(u0.x); a[1]=f2b(u0.y); a[2]=f2b(u0.z); a[3]=f2b(u0.w);
        a[4]=f2b(u1.x); a[5]=f2b(u1.y); a[6]=f2b(u1.z); a[7]=f2b(u1.w);
        af[kk]=a;
    }
    frag4f zacc[16];
    #pragma unroll
    for (int nt=0;nt<16;nt++){ frag4f zv = {0.f,0.f,0.f,0.f}; zacc[nt]=zv; }
    const short* w1b = W1p + ((size_t)p*32*64 + lane)*8;
    #pragma unroll
    for (int nt=0;nt<16;nt++)
        #pragma unroll
        for (int kk=0;kk<2;kk++){
            frag8 b = *(const frag8*)(w1b + (size_t)(nt*2+kk)*64*8);
            zacc[nt] = MFMA(af[kk], b, zacc[nt]);
        }
    // h -> LDS (row-major) and hT -> global (transposed, packed 4 m-consecutive)
    #pragma unroll
    for (int nt=0;nt<16;nt++){
        short4v hp;
        #pragma unroll
        for (int r=0;r<4;r++){
            float h = gelu_f(zacc[nt][r]);
            hl[(w*16 + q*4 + r)*264 + nt*16 + ln] = f2b(h);
            hp[r] = f2b(h);
        }
        *(short4v*)(hT + ((size_t)p*HID + nt*16+ln)*CH + (m0 + w*16 + q*4)) = hp;
    }
    __syncthreads();

    // ---- out = h @ W2 ; e = (out - y)*s ----
    frag8 hfr[8];
    #pragma unroll
    for (int kk=0;kk<8;kk++)
        hfr[kk] = *(const frag8*)(&hl[(w*16+ln)*264 + kk*32 + q*8]);
    const short* w2b = W2p + ((size_t)p*32*64 + lane)*8;
    #pragma unroll
    for (int nt=0;nt<4;nt++){
        frag4f oc = {0.f,0.f,0.f,0.f};
        #pragma unroll
        for (int kk=0;kk<8;kk++){
            frag8 b = *(const frag8*)(w2b + (size_t)(nt*8+kk)*64*8);
            oc = MFMA(hfr[kk], b, oc);
        }
        short4v ep;
        #pragma unroll
        for (int r=0;r<4;r++){
            int m = m0 + w*16 + q*4 + r;
            float y = vin[((size_t)p*NTOK + (size_t)t*CH + m)*DD + nt*16 + ln];
            float e = (oc[r] - y)*INV_CD;
            el[(w*16+q*4+r)*72 + nt*16+ln] = f2b(e);
            ep[r] = f2b(e);
        }
        *(short4v*)(eT + ((size_t)p*DD + nt*16+ln)*CH + (m0 + w*16 + q*4)) = ep;
    }
    __syncthreads();

    // ---- dz = (e @ W2^T) * gelu'(z) -> dzT ----
    frag8 efr[2];
    #pragma unroll
    for (int kk=0;kk<2;kk++)
        efr[kk] = *(const frag8*)(&el[(w*16+ln)*72 + kk*32 + q*8]);
    const short* w2tb = W2tp + ((size_t)p*32*64 + lane)*8;
    #pragma unroll
    for (int nt=0;nt<16;nt++){
        frag4f dc = {0.f,0.f,0.f,0.f};
        #pragma unroll
        for (int kk=0;kk<2;kk++){
            frag8 b = *(const frag8*)(w2tb + (size_t)(nt*2+kk)*64*8);
            dc = MFMA(efr[kk], b, dc);
        }
        short4v dp;
        #pragma unroll
        for (int r=0;r<4;r++)
            dp[r] = f2b(dc[r] * gelu_grad(zacc[nt][r]));
        *(short4v*)(dzT + ((size_t)p*HID + nt*16+ln)*CH + (m0 + w*16 + q*4)) = dp;
    }
}

// dW1 = X^T dz (M=64 d, N=256 e', K=512 m), split-K=4, atomic -= into W1s.
// X transposed through LDS; dz read as b128 frags from dzT.
__global__ __launch_bounds__(256) void k_dW1(const float* __restrict__ kin,
                                             const short* __restrict__ dzT,
                                             float* __restrict__ W1s, int t){
    int p = blockIdx.x >> 2, ks = blockIdx.x & 3;
    int tid = threadIdx.x;
    int w = tid >> 6, lane = tid & 63, q = lane >> 4, ln = lane & 15;
    __shared__ short xT[64*136];   // X^T tile [d][m], pad 136 (17 KB)
    const float* xb = kin + ((size_t)p*NTOK + (size_t)t*CH + ks*128)*DD;
    {
        int d4 = tid >> 4, mr = tid & 15;
        for (int mi=0; mi<8; mi++){
            int m = mi*16 + mr;
            float4 u = *(const float4*)(xb + m*DD + d4*4);
            xT[(d4*4+0)*136 + m] = f2b(u.x);
            xT[(d4*4+1)*136 + m] = f2b(u.y);
            xT[(d4*4+2)*136 + m] = f2b(u.z);
            xT[(d4*4+3)*136 + m] = f2b(u.w);
        }
    }
    __syncthreads();
    frag8 afr[4];
    #pragma unroll
    for (int kk=0;kk<4;kk++)
        afr[kk] = *(const frag8*)(&xT[(w*16+ln)*136 + kk*32 + q*8]);
    const short* dzb = dzT + (size_t)p*HID*CH;
    frag4f acc[16];
    #pragma unroll
    for (int nt=0;nt<16;nt++){ frag4f zv = {0.f,0.f,0.f,0.f}; acc[nt]=zv; }
    #pragma unroll
    for (int nt=0;nt<16;nt++)
        #pragma unroll
        for (int kk=0;kk<4;kk++){
            frag8 b = *(const frag8*)(dzb + (size_t)(nt*16+ln)*CH + ks*128 + kk*32 + q*8);
            acc[nt] = MFMA(afr[kk], b, acc[nt]);
        }
    float* w1 = W1s + (size_t)p*16384;
    #pragma unroll
    for (int nt=0;nt<16;nt++)
        #pragma unroll
        for (int r=0;r<4;r++)
            atomicAdd(&w1[(w*16+q*4+r)*HID + nt*16+ln], -acc[nt][r]);
}

// dW2 = h^T e (M=256 e', N=64 o, K=512 m), split-K=4, atomic -= into W2s.
// Both operands direct b128 global frags (hT, eT).
__global__ __launch_bounds__(256) void k_dW2(const short* __restrict__ hT,
                                             const short* __restrict__ eT,
                                             float* __restrict__ W2s){
    int p = blockIdx.x >> 2, ks = blockIdx.x & 3;
    int tid = threadIdx.x;
    int w = tid >> 6, lane = tid & 63, q = lane >> 4, ln = lane & 15;
    const short* hb = hT + (size_t)p*HID*CH + ks*128;
    const short* eb = eT + (size_t)p*DD*CH  + ks*128;
    frag8 bfr[16];                       // B-frags (nt x kk), reused across 4 e'-tiles
    #pragma unroll
    for (int nt=0;nt<4;nt++)
        #pragma unroll
        for (int kk=0;kk<4;kk++)
            bfr[nt*4+kk] = *(const frag8*)(eb + (size_t)(nt*16+ln)*CH + kk*32 + q*8);
    frag4f acc[16];
    #pragma unroll
    for (int i=0;i<16;i++){ frag4f zv = {0.f,0.f,0.f,0.f}; acc[i]=zv; }
    #pragma unroll
    for (int i=0;i<4;i++){               // e'-tile = w*4+i
        #pragma unroll
        for (int kk=0;kk<4;kk++){
            frag8 a = *(const frag8*)(hb + (size_t)(((w*4+i)*16)+ln)*CH + kk*32 + q*8);
            #pragma unroll
            for (int nt=0;nt<4;nt++)
                acc[i*4+nt] = MFMA(a, bfr[nt*4+kk], acc[i*4+nt]);
        }
    }
    float* w2 = W2s + (size_t)p*16384;
    #pragma unroll
    for (int i=0;i<4;i++)
        #pragma unroll
        for (int nt=0;nt<4;nt++)
            #pragma unroll
            for (int r=0;r<4;r++)
                atomicAdd(&w2[((w*4+i)*16+q*4+r)*DD + nt*16+ln], -acc[i*4+nt][r]);
}

// out = gelu(q @ W1_final) @ W2_final -> (B, N, H*D) f32.
__global__ __launch_bounds__(256) void k_apply(const float* __restrict__ qin,
                                               const short* __restrict__ W1p,
                                               const short* __restrict__ W2p,
                                               float* __restrict__ out){
    int p = blockIdx.x >> 5, mt = blockIdx.x & 31;
    int tid = threadIdx.x;
    int w = tid >> 6, lane = tid & 63, q = lane >> 4, ln = lane & 15;
    int m0 = mt*64;
    int b = p >> 4, h = p & 15;
    __shared__ short hl[64*264];
    const float* xbase = qin + ((size_t)p*NTOK + m0 + w*16 + ln)*DD;
    frag8 af[2];
    #pragma unroll
    for (int kk=0;kk<2;kk++){
        const float* xr = xbase + kk*32 + q*8;
        float4 u0 = *(const float4*)xr;
        float4 u1 = *(const float4*)(xr+4);
        frag8 a;
        a[0]=f2b(u0.x); a[1]=f2b(u0.y); a[2]=f2b(u0.z); a[3]=f2b(u0.w);
        a[4]=f2b(u1.x); a[5]=f2b(u1.y); a[6]=f2b(u1.z); a[7]=f2b(u1.w);
        af[kk]=a;
    }
    const short* w1b = W1p + ((size_t)p*32*64 + lane)*8;
    #pragma unroll
    for (int nt=0;nt<16;nt++){
        frag4f zc = {0.f,0.f,0.f,0.f};
        #pragma unroll
        for (int kk=0;kk<2;kk++){
            frag8 bfr = *(const frag8*)(w1b + (size_t)(nt*2+kk)*64*8);
            zc = MFMA(af[kk], bfr, zc);
        }
        #pragma unroll
        for (int r=0;r<4;r++)
            hl[(w*16 + q*4 + r)*264 + nt*16 + ln] = f2b(gelu_f(zc[r]));
    }
    __syncthreads();
    frag8 hfr[8];
    #pragma unroll
    for (int kk=0;kk<8;kk++)
        hfr[kk] = *(const frag8*)(&hl[(w*16+ln)*264 + kk*32 + q*8]);
    const short* w2b = W2p + ((size_t)p*32*64 + lane)*8;
    #pragma unroll
    for (int nt=0;nt<4;nt++){
        frag4f oc = {0.f,0.f,0.f,0.f};
        #pragma unroll
        for (int kk=0;kk<8;kk++){
            frag8 bfr = *(const frag8*)(w2b + (size_t)(nt*8+kk)*64*8);
            oc = MFMA(hfr[kk], bfr, oc);
        }
        #pragma unroll
        for (int r=0;r<4;r++){
            int n = m0 + w*16 + q*4 + r;
            out[((size_t)b*NTOK + n)*(HH*DD) + h*DD + nt*16 + ln] = oc[r];
        }
    }
}

extern "C" void kernel_launch(void* const* d_in, const int* in_sizes, int n_in,
                              void* d_out, int out_size, void* d_ws, size_t ws_size,
                              hipStream_t stream) {
    (void)in_sizes; (void)n_in; (void)out_size; (void)ws_size;
    const float* q  = (const float*)d_in[0];
    const float* k  = (const float*)d_in[1];
    const float* v  = (const float*)d_in[2];
    const float* W1 = (const float*)d_in[3];
    const float* W2 = (const float*)d_in[4];
    float* out = (float*)d_out;

    // ws layout (37.8 MB): f32 masters + pre-swizzled bf16 weights + eT.
    float* W1s = (float*)d_ws;                       // NP*16384 f32
    float* W2s = W1s + (size_t)NP*16384;             // NP*16384 f32
    short* W1p  = (short*)(W2s + (size_t)NP*16384);  // NP*32*64*8 bf16
    short* W2p  = W1p + (size_t)NP*16384;
    short* W2tp = W2p + (size_t)NP*16384;
    short* eT   = W2tp + (size_t)NP*16384;           // NP*64*512 bf16
    // d_out scratch: hT (NP*256*512 bf16) + dzT (same) = exactly out_size f32 bytes.
    short* hT  = (short*)d_out;
    short* dzT = hT + (size_t)NP*HID*CH;

    k_init<<<NP*16384/256, 256, 0, stream>>>(W1, W2, W1s, W2s);
    for (int t=0; t<NIT; t++){
        k_castW<<<NP*96*64/256, 256, 0, stream>>>(W1s, W2s, W1p, W2p, W2tp);
        k_fwd  <<<NP*8,  256, 0, stream>>>(k, v, W1p, W2p, W2tp, eT, hT, dzT, t);
        k_dW2  <<<NP*4,  256, 0, stream>>>(hT, eT, W2s);
        k_dW1  <<<NP*4,  256, 0, stream>>>(k, dzT, W1s, t);
    }
    k_castW<<<NP*96*64/256, 256, 0, stream>>>(W1s, W2s, W1p, W2p, W2tp);
    k_apply<<<NP*32, 256, 0, stream>>>(q, W1p, W2p, out);
}